// Round 3
// baseline (220.913 us; speedup 1.0000x reference)
//
#include <hip/hip_runtime.h>

// x [B,C,H,W] fp32, guide [B,1,H,W] fp32.
// out[b,c,h,t] = max_{j<=t} x[b,c,h,j]*guide[b,0,h,j]  (cummax along W)
#define PB 8
#define PC 256
#define PH 128
#define PW 128
#define TOTAL_ROWS (PB * PC * PH)                // 262144
#define ROWS_PER_SEG 4
#define ROW_GROUPS (TOTAL_ROWS / ROWS_PER_SEG)   // 65536
#define NITER 4
#define SEGS (ROW_GROUPS / NITER)                // 16384 resident segments
#define KSTRIDE ((size_t)(PH * PW / 4))          // row stride in vfloat4

// Native clang vector type — __builtin_nontemporal_* requires this.
typedef float vfloat4 __attribute__((ext_vector_type(4)));

// Persistent-loop rewrite. Rounds 0 and 2 (one-shot threads, different MLP
// structures) both plateau at ~65 us ~= 3.3 TB/s with VALUBusy 7%: waves
// drain one latency, die, and wait re-dispatch (duty-cycle starvation).
// The loop-based float4-copy ubench does 6.3 TB/s on the same mixed
// read+write stream. Here each 32-lane segment processes NITER=4
// row-groups with two named register buffers, hand-unrolled so the load
// batch for iteration t+1 is in flight while iteration t computes/stores
// (compiler emits counted vmcnt waits). Iteration t covers a contiguous
// quarter of the tensor -> chip-level streaming order preserved.
struct Seg {
    vfloat4 x0, x1, x2, x3;   // four channel-adjacent rows (share one guide)
    vfloat4 g;
};

__device__ __forceinline__ void seg_load(Seg& s, const float* __restrict__ x,
                                         const float* __restrict__ guide,
                                         int rg, int sub)
{
    const int h  = rg & (PH - 1);
    const int g4 = rg >> 7;            // b*64 + c4
    const int b  = rg >> 13;
    const size_t xoff = (((size_t)g4 << 2) * PH + h) * PW + sub * 4;
    const size_t goff = ((size_t)b * PH + h) * PW + sub * 4;
    const vfloat4* xp = (const vfloat4*)(x + xoff);
    // 4 independent NT x streams (evict-first, pure streaming) + cached guide
    s.x0 = __builtin_nontemporal_load(xp);
    s.x1 = __builtin_nontemporal_load(xp + KSTRIDE);
    s.x2 = __builtin_nontemporal_load(xp + 2 * KSTRIDE);
    s.x3 = __builtin_nontemporal_load(xp + 3 * KSTRIDE);
    s.g  = *(const vfloat4*)(guide + goff);
}

__device__ __forceinline__ void seg_cs(const Seg& s, float* __restrict__ out,
                                       int rg, int sub)
{
    const int h  = rg & (PH - 1);
    const int g4 = rg >> 7;
    const size_t xoff = (((size_t)g4 << 2) * PH + h) * PW + sub * 4;
    vfloat4* op = (vfloat4*)(out + xoff);

    vfloat4 ov0, ov1, ov2, ov3;
    float t0, t1, t2, t3;

    // Local inclusive max-scan over each lane's 4 owned elems, per row.
    ov0.x = s.x0.x * s.g.x;
    ov0.y = fmaxf(ov0.x, s.x0.y * s.g.y);
    ov0.z = fmaxf(ov0.y, s.x0.z * s.g.z);
    ov0.w = fmaxf(ov0.z, s.x0.w * s.g.w);
    t0 = ov0.w;
    ov1.x = s.x1.x * s.g.x;
    ov1.y = fmaxf(ov1.x, s.x1.y * s.g.y);
    ov1.z = fmaxf(ov1.y, s.x1.z * s.g.z);
    ov1.w = fmaxf(ov1.z, s.x1.w * s.g.w);
    t1 = ov1.w;
    ov2.x = s.x2.x * s.g.x;
    ov2.y = fmaxf(ov2.x, s.x2.y * s.g.y);
    ov2.z = fmaxf(ov2.y, s.x2.z * s.g.z);
    ov2.w = fmaxf(ov2.z, s.x2.w * s.g.w);
    t2 = ov2.w;
    ov3.x = s.x3.x * s.g.x;
    ov3.y = fmaxf(ov3.x, s.x3.y * s.g.y);
    ov3.z = fmaxf(ov3.y, s.x3.z * s.g.z);
    ov3.w = fmaxf(ov3.z, s.x3.w * s.g.w);
    t3 = ov3.w;

    // Four interleaved branchless 32-lane inclusive max-scans.
    // __shfl_up below the segment floor returns own value; fmax(x,x)==x.
    #pragma unroll
    for (int d = 1; d < 32; d <<= 1) {
        float u0 = __shfl_up(t0, d, 32);
        float u1 = __shfl_up(t1, d, 32);
        float u2 = __shfl_up(t2, d, 32);
        float u3 = __shfl_up(t3, d, 32);
        t0 = fmaxf(t0, u0);
        t1 = fmaxf(t1, u1);
        t2 = fmaxf(t2, u2);
        t3 = fmaxf(t3, u3);
    }

    float p0 = __shfl_up(t0, 1, 32);
    float p1 = __shfl_up(t1, 1, 32);
    float p2 = __shfl_up(t2, 1, 32);
    float p3 = __shfl_up(t3, 1, 32);
    if (sub == 0) {                      // v_cndmask, no branch
        p0 = -__builtin_inff(); p1 = -__builtin_inff();
        p2 = -__builtin_inff(); p3 = -__builtin_inff();
    }
    ov0.x = fmaxf(ov0.x, p0); ov0.y = fmaxf(ov0.y, p0);
    ov0.z = fmaxf(ov0.z, p0); ov0.w = fmaxf(ov0.w, p0);
    ov1.x = fmaxf(ov1.x, p1); ov1.y = fmaxf(ov1.y, p1);
    ov1.z = fmaxf(ov1.z, p1); ov1.w = fmaxf(ov1.w, p1);
    ov2.x = fmaxf(ov2.x, p2); ov2.y = fmaxf(ov2.y, p2);
    ov2.z = fmaxf(ov2.z, p2); ov2.w = fmaxf(ov2.w, p2);
    ov3.x = fmaxf(ov3.x, p3); ov3.y = fmaxf(ov3.y, p3);
    ov3.z = fmaxf(ov3.z, p3); ov3.w = fmaxf(ov3.w, p3);

    __builtin_nontemporal_store(ov0, op);
    __builtin_nontemporal_store(ov1, op + KSTRIDE);
    __builtin_nontemporal_store(ov2, op + 2 * KSTRIDE);
    __builtin_nontemporal_store(ov3, op + 3 * KSTRIDE);
}

__global__ __launch_bounds__(256) void i5pool_cummax_kernel(
    const float* __restrict__ x,
    const float* __restrict__ guide,
    float* __restrict__ out)
{
    const int tid = blockIdx.x * blockDim.x + threadIdx.x;
    const int sub = tid & 31;          // lane-within-row (owns elems 4*sub..)
    const int s0  = tid >> 5;          // resident segment id, 0..SEGS-1

    Seg A, B;
    // Software pipeline, hand-unrolled (all buffer refs static — rule #20):
    seg_load(A, x, guide, s0,            sub);   // iter 0 in flight
    seg_load(B, x, guide, s0 + SEGS,     sub);   // iter 1 in flight
    seg_cs(A, out, s0,            sub);          // counted vmcnt wait only
    seg_load(A, x, guide, s0 + 2 * SEGS, sub);   // iter 2 in flight
    seg_cs(B, out, s0 + SEGS,     sub);
    seg_load(B, x, guide, s0 + 3 * SEGS, sub);   // iter 3 in flight
    seg_cs(A, out, s0 + 2 * SEGS, sub);
    seg_cs(B, out, s0 + 3 * SEGS, sub);
}

extern "C" void kernel_launch(void* const* d_in, const int* in_sizes, int n_in,
                              void* d_out, int out_size, void* d_ws, size_t ws_size,
                              hipStream_t stream) {
    const float* x     = (const float*)d_in[0];
    const float* guide = (const float*)d_in[1];
    float* out = (float*)d_out;

    // SEGS segments * 32 lanes = 524288 threads -> 2048 blocks (8 per CU),
    // each segment loops over NITER=4 row-groups with a 2-deep pipeline.
    const int total_threads = SEGS * 32;
    const int block = 256;
    const int grid = total_threads / block;  // 2048

    i5pool_cummax_kernel<<<grid, block, 0, stream>>>(x, guide, out);
}